// Round 3
// baseline (256.957 us; speedup 1.0000x reference)
//
#include <hip/hip_runtime.h>
#include <math.h>

#define S_   4096
#define H_   8
#define D_   64
#define HD_  512
#define NCH  256   // chunks per batch
#define LCH  16    // seq steps per chunk
#define RC   128   // rows per chunk = LCH*H_

typedef __bf16 bf16x8 __attribute__((ext_vector_type(8)));
typedef float  f32x4  __attribute__((ext_vector_type(4)));

__device__ __forceinline__ float sigm(float v) { return 1.f / (1.f + __expf(-v)); }

// ---------------- K0: transpose weights to bf16 [n][k] ----------------
__global__ __launch_bounds__(256) void k_wt(const float* __restrict__ Wh,
                                            const float* __restrict__ Wo,
                                            __bf16* __restrict__ Wth,
                                            __bf16* __restrict__ Wto) {
  int idx = blockIdx.x * 256 + threadIdx.x;   // 0..32767
  if (idx < 24576) {
    int k = idx / 192, n = idx % 192;
    Wth[n * 128 + k] = (__bf16)Wh[idx];
  } else {
    int j = idx - 24576;                       // W_og[k][n], n<64
    int k = j >> 6, n = j & 63;
    Wto[n * 128 + k] = (__bf16)Wo[j];
  }
}

// ------- K1: per-chunk fp32 sums of x AND emit bf16 x-half of Abf -------
__global__ __launch_bounds__(512) void k_pre(const float* __restrict__ x,
                                             float* __restrict__ sums,
                                             __bf16* __restrict__ Abf) {
  const int t = threadIdx.x;
  const int h = t >> 6, d = t & 63;
  const size_t r0 = (size_t)blockIdx.x * RC;          // global row base
  const float* p = x + r0 * 64 + t;                   // x rows are 64 wide? no:
  // x is [b][s][h][d] flat; chunk rows r0..r0+127 correspond to x offset r0*64.
  float acc = 0.f;
  #pragma unroll
  for (int i = 0; i < LCH; ++i) {
    float v = p[(size_t)i * HD_];
    acc += v;
    Abf[(r0 + (size_t)i * H_ + h) * 128 + d] = (__bf16)v;
  }
  sums[(size_t)blockIdx.x * HD_ + t] = acc;
}

// ---------------- K2: exclusive scan of chunk sums over c ----------------
__global__ __launch_bounds__(512) void k_scan_offsets(const float* __restrict__ sums,
                                                      float* __restrict__ offs) {
  const int b = blockIdx.x, t = threadIdx.x;
  float run = 0.f;
  #pragma unroll 16
  for (int c = 0; c < NCH; ++c) {
    size_t idx = ((size_t)b * NCH + c) * HD_ + t;
    float v = sums[idx];
    offs[idx] = run;
    run += v;
  }
}

// ---------------- K3: prefix + LayerNorm, emit bf16 ln-half of Abf ----------
__global__ __launch_bounds__(512) void k_ln(const float* __restrict__ offs,
                                            const float* __restrict__ gamma,
                                            const float* __restrict__ beta,
                                            __bf16* __restrict__ Abf) {
  __shared__ float2 red[2][8];
  const int t = threadIdx.x;
  const int h = t >> 6, d = t & 63;
  const size_t r0 = (size_t)blockIdx.x * RC;
  float run = offs[(size_t)blockIdx.x * HD_ + t];
  const float g = gamma[t], be = beta[t];
  for (int i = 0; i < LCH; ++i) {
    size_t row = r0 + (size_t)i * H_ + h;
    float xv = (float)Abf[row * 128 + d];
    float v = run, v2 = run * run;
    #pragma unroll
    for (int o = 32; o; o >>= 1) { v += __shfl_xor(v, o); v2 += __shfl_xor(v2, o); }
    if ((t & 63) == 0) red[i & 1][t >> 6] = make_float2(v, v2);
    __syncthreads();
    float s1 = 0.f, s2 = 0.f;
    #pragma unroll
    for (int w = 0; w < 8; ++w) { s1 += red[i & 1][w].x; s2 += red[i & 1][w].y; }
    float m = s1 * (1.f / HD_);
    float var = fmaf(-m, m, s2 * (1.f / HD_));
    float inv = rsqrtf(var + 1e-5f);
    Abf[row * 128 + 64 + d] = (__bf16)((run - m) * inv * g + be);
    run += xv;
  }
}

// -------- K4: gates MFMA GEMM (h-major tiles) -> chunk compose (cA,cB) ------
// Block = one chunk (128 rows). Tile mt = head h = wave*2+mi, rows = 16 s-steps.
__global__ __launch_bounds__(256) void k_gates(const __bf16* __restrict__ Abf,
                                               const __bf16* __restrict__ Wt,
                                               const float* __restrict__ bh,
                                               float* __restrict__ cA,
                                               float* __restrict__ cB) {
  const int t = threadIdx.x;
  const int wave = t >> 6, lane = t & 63;
  const int quad = lane >> 4, l16 = lane & 15;
  const size_t r0 = (size_t)blockIdx.x * RC;

  f32x4 acc[2][12];
  #pragma unroll
  for (int i = 0; i < 2; ++i)
    #pragma unroll
    for (int j = 0; j < 12; ++j) acc[i][j] = (f32x4){0.f, 0.f, 0.f, 0.f};

  #pragma unroll
  for (int ks = 0; ks < 4; ++ks) {
    bf16x8 bfrag[12];
    #pragma unroll
    for (int nt = 0; nt < 12; ++nt)
      bfrag[nt] = *(const bf16x8*)(Wt + (nt * 16 + l16) * 128 + ks * 32 + quad * 8);
    #pragma unroll
    for (int mi = 0; mi < 2; ++mi) {
      int h = wave * 2 + mi;
      // A row for lane: s = l16, head h -> global row r0 + l16*8 + h
      bf16x8 afrag = *(const bf16x8*)(Abf + (r0 + l16 * H_ + h) * 128 + ks * 32 + quad * 8);
      #pragma unroll
      for (int nt = 0; nt < 12; ++nt)
        acc[mi][nt] = __builtin_amdgcn_mfma_f32_16x16x32_bf16(afrag, bfrag[nt], acc[mi][nt], 0, 0, 0);
    }
  }

  // epilogue: activations + in-lane compose (4 consecutive s) + cross-quad compose
  #pragma unroll
  for (int mi = 0; mi < 2; ++mi) {
    int h = wave * 2 + mi;
    #pragma unroll
    for (int nt = 0; nt < 4; ++nt) {
      int d = nt * 16 + l16;
      float bi = bh[d], bf = bh[64 + d], bhv = bh[128 + d];
      float A = 1.f, Bv = 0.f;
      #pragma unroll
      for (int r = 0; r < 4; ++r) {
        float f = sigm(acc[mi][nt + 4][r] + bf);
        float g = sigm(acc[mi][nt][r] + bi) * fmaxf(acc[mi][nt + 8][r] + bhv, 0.f);
        A = f * A;
        Bv = fmaf(f, Bv, g);
      }
      // gather all 4 quad summaries (quad q covers s in [q*4, q*4+4))
      float At = 0.f, Bt = 0.f;
      #pragma unroll
      for (int q = 0; q < 4; ++q) {
        float Aq = __shfl(A, q * 16 + l16);
        float Bq = __shfl(Bv, q * 16 + l16);
        if (q == 0) { At = Aq; Bt = Bq; }
        else { At = Aq * At; Bt = fmaf(Aq, Bt, Bq); }
      }
      if (quad == 0) {
        cA[(size_t)blockIdx.x * HD_ + h * 64 + d] = At;
        cB[(size_t)blockIdx.x * HD_ + h * 64 + d] = Bt;
      }
    }
  }
}

// ---------------- K5: cross-chunk scan -> cin ----------------
__global__ __launch_bounds__(512) void k_cell_scan(const float* __restrict__ cA,
                                                   const float* __restrict__ cB,
                                                   const float* __restrict__ initcx,
                                                   float* __restrict__ cin) {
  const int b = blockIdx.x, t = threadIdx.x;
  float run = initcx[t];
  #pragma unroll 16
  for (int c = 0; c < NCH; ++c) {
    size_t idx = ((size_t)b * NCH + c) * HD_ + t;
    float a = cA[idx], bb = cB[idx];
    cin[idx] = run;
    run = fmaf(a, run, bb);
  }
}

// ---- K6: recompute gates GEMM + in-reg cell scan + og GEMM + out=og*cell ----
__global__ __launch_bounds__(256) void k_og(const __bf16* __restrict__ Abf,
                                            const __bf16* __restrict__ Wth,
                                            const float* __restrict__ bh,
                                            const __bf16* __restrict__ Wto,
                                            const float* __restrict__ bo,
                                            const float* __restrict__ cin,
                                            float* __restrict__ out) {
  __shared__ float cl[RC * 68];
  const int t = threadIdx.x;
  const int wave = t >> 6, lane = t & 63;
  const int quad = lane >> 4, l16 = lane & 15;
  const size_t r0 = (size_t)blockIdx.x * RC;

  f32x4 acc[2][12];
  #pragma unroll
  for (int i = 0; i < 2; ++i)
    #pragma unroll
    for (int j = 0; j < 12; ++j) acc[i][j] = (f32x4){0.f, 0.f, 0.f, 0.f};

  #pragma unroll
  for (int ks = 0; ks < 4; ++ks) {
    bf16x8 bfrag[12];
    #pragma unroll
    for (int nt = 0; nt < 12; ++nt)
      bfrag[nt] = *(const bf16x8*)(Wth + (nt * 16 + l16) * 128 + ks * 32 + quad * 8);
    #pragma unroll
    for (int mi = 0; mi < 2; ++mi) {
      int h = wave * 2 + mi;
      bf16x8 afrag = *(const bf16x8*)(Abf + (r0 + l16 * H_ + h) * 128 + ks * 32 + quad * 8);
      #pragma unroll
      for (int nt = 0; nt < 12; ++nt)
        acc[mi][nt] = __builtin_amdgcn_mfma_f32_16x16x32_bf16(afrag, bfrag[nt], acc[mi][nt], 0, 0, 0);
    }
  }

  // epilogue: f,g -> in-lane scan + cross-quad exclusive prefix + cin seed
  #pragma unroll
  for (int mi = 0; mi < 2; ++mi) {
    int h = wave * 2 + mi;
    #pragma unroll
    for (int nt = 0; nt < 4; ++nt) {
      int d = nt * 16 + l16;
      float bi = bh[d], bf = bh[64 + d], bhv = bh[128 + d];
      float fr[4], gr[4];
      float A = 1.f, Bv = 0.f;
      #pragma unroll
      for (int r = 0; r < 4; ++r) {
        fr[r] = sigm(acc[mi][nt + 4][r] + bf);
        gr[r] = sigm(acc[mi][nt][r] + bi) * fmaxf(acc[mi][nt + 8][r] + bhv, 0.f);
        A = fr[r] * A;
        Bv = fmaf(fr[r], Bv, gr[r]);
      }
      float c = cin[(size_t)blockIdx.x * HD_ + h * 64 + d];  // chunk-entry state
      #pragma unroll
      for (int q = 0; q < 3; ++q) {
        float Aq = __shfl(A, q * 16 + l16);
        float Bq = __shfl(Bv, q * 16 + l16);
        if (q < quad) c = fmaf(Aq, c, Bq);
      }
      #pragma unroll
      for (int r = 0; r < 4; ++r) {
        c = fmaf(fr[r], c, gr[r]);
        cl[(h * 16 + quad * 4 + r) * 68 + d] = c;  // rowl = h*16 + s
      }
    }
  }
  __syncthreads();

  // og GEMM: A = [x | cell]
  f32x4 acc2[2][4];
  #pragma unroll
  for (int i = 0; i < 2; ++i)
    #pragma unroll
    for (int j = 0; j < 4; ++j) acc2[i][j] = (f32x4){0.f, 0.f, 0.f, 0.f};

  #pragma unroll
  for (int ks = 0; ks < 4; ++ks) {
    bf16x8 bfrag[4];
    #pragma unroll
    for (int nt = 0; nt < 4; ++nt)
      bfrag[nt] = *(const bf16x8*)(Wto + (nt * 16 + l16) * 128 + ks * 32 + quad * 8);
    #pragma unroll
    for (int mi = 0; mi < 2; ++mi) {
      int h = wave * 2 + mi;
      bf16x8 afrag;
      if (ks < 2) {
        afrag = *(const bf16x8*)(Abf + (r0 + l16 * H_ + h) * 128 + ks * 32 + quad * 8);
      } else {
        const float* src = &cl[(h * 16 + l16) * 68 + (ks - 2) * 32 + quad * 8];
        #pragma unroll
        for (int j = 0; j < 8; ++j) afrag[j] = (__bf16)src[j];
      }
      #pragma unroll
      for (int nt = 0; nt < 4; ++nt)
        acc2[mi][nt] = __builtin_amdgcn_mfma_f32_16x16x32_bf16(afrag, bfrag[nt], acc2[mi][nt], 0, 0, 0);
    }
  }

  #pragma unroll
  for (int mi = 0; mi < 2; ++mi) {
    int h = wave * 2 + mi;
    #pragma unroll
    for (int nt = 0; nt < 4; ++nt) {
      int d = nt * 16 + l16;
      float bv = bo[d];
      #pragma unroll
      for (int r = 0; r < 4; ++r) {
        int s = quad * 4 + r;
        float og = sigm(acc2[mi][nt][r] + bv);
        float cv = cl[(h * 16 + s) * 68 + d];
        out[(r0 + (size_t)s * H_ + h) * 64 + d] = og * cv;
      }
    }
  }
}

extern "C" void kernel_launch(void* const* d_in, const int* in_sizes, int n_in,
                              void* d_out, int out_size, void* d_ws, size_t ws_size,
                              hipStream_t stream) {
  const float* x      = (const float*)d_in[0];
  const float* W_hid  = (const float*)d_in[1];
  const float* b_hid  = (const float*)d_in[2];
  const float* W_og   = (const float*)d_in[3];
  const float* b_og   = (const float*)d_in[4];
  const float* gamma  = (const float*)d_in[5];
  const float* beta   = (const float*)d_in[6];
  const float* initcx = (const float*)d_in[7];
  float* out = (float*)d_out;
  float* ws  = (float*)d_ws;

  const size_t SM = 524288;  // B*NCH*HD floats (2 MB)
  float*  sums = ws;
  float*  offs = sums + SM;
  float*  cA   = offs + SM;
  float*  cB   = cA + SM;
  float*  cin  = cB + SM;
  __bf16* Abf  = (__bf16*)(cin + SM);        // [131072][128] bf16 = 33.5 MB
  __bf16* Wth  = (__bf16*)(Abf + (size_t)131072 * 128);
  __bf16* Wto  = Wth + 24576;

  k_wt          <<<128,  256, 0, stream>>>(W_hid, W_og, Wth, Wto);
  k_pre         <<<1024, 512, 0, stream>>>(x, sums, Abf);
  k_scan_offsets<<<4,    512, 0, stream>>>(sums, offs);
  k_ln          <<<1024, 512, 0, stream>>>(offs, gamma, beta, Abf);
  k_gates       <<<1024, 256, 0, stream>>>(Abf, Wth, b_hid, cA, cB);
  k_cell_scan   <<<4,    512, 0, stream>>>(cA, cB, initcx, cin);
  k_og          <<<1024, 256, 0, stream>>>(Abf, Wth, b_hid, Wto, b_og, cin, out);
}

// Round 4
// 224.664 us; speedup vs baseline: 1.1437x; 1.1437x over previous
//
#include <hip/hip_runtime.h>
#include <math.h>

#define S_   4096
#define H_   8
#define D_   64
#define HD_  512
#define NCH  256   // chunks per batch
#define LCH  16    // seq steps per chunk
#define RC   128   // rows per chunk = LCH*H_

typedef __bf16 bf16x8 __attribute__((ext_vector_type(8)));
typedef float  f32x4  __attribute__((ext_vector_type(4)));

__device__ __forceinline__ float sigm(float v) { return 1.f / (1.f + __expf(-v)); }

// ---- K0: weights -> bf16, pre-swizzled into per-wave fragment order --------
// dst layout: [ks][nt][lane][8] so a wave's bfrag load is one contiguous 1KB.
__global__ __launch_bounds__(256) void k_wt(const float* __restrict__ Wh,
                                            const float* __restrict__ Wo,
                                            __bf16* __restrict__ WthS,
                                            __bf16* __restrict__ WtoS) {
  int idx = blockIdx.x * 256 + threadIdx.x;   // 0..32767
  if (idx < 24576) {
    int k = idx / 192, n = idx % 192;          // Wh[k][n], coalesced in n
    int nt = n >> 4, l16 = n & 15;
    int ks = k >> 5, quad = (k >> 3) & 3, j = k & 7;
    WthS[(((ks * 12 + nt) * 64) + quad * 16 + l16) * 8 + j] = (__bf16)Wh[idx];
  } else {
    int j2 = idx - 24576;                      // Wo[k][n], n<64
    int k = j2 >> 6, n = j2 & 63;
    int nt = n >> 4, l16 = n & 15;
    int ks = k >> 5, quad = (k >> 3) & 3, j = k & 7;
    WtoS[(((ks * 4 + nt) * 64) + quad * 16 + l16) * 8 + j] = (__bf16)Wo[j2];
  }
}

// ---- K1: chunk sums + emit bf16 x-half of transposed Abf -------------------
// Abf row index rT = (b*8+h)*4096 + s  (h-major, s contiguous)
__global__ __launch_bounds__(512) void k_pre(const float* __restrict__ x,
                                             float* __restrict__ sums,
                                             __bf16* __restrict__ Abf) {
  const int t = threadIdx.x, h = t >> 6, d = t & 63;
  const int b = blockIdx.x >> 8, c = blockIdx.x & 255;
  const float* p = x + ((size_t)(b * S_ + c * LCH)) * HD_ + t;
  const size_t rT0 = ((size_t)(b * H_ + h)) * S_ + c * LCH;
  float acc = 0.f;
  #pragma unroll
  for (int i = 0; i < LCH; ++i) {
    float v = p[(size_t)i * HD_];
    acc += v;
    Abf[(rT0 + i) * 128 + d] = (__bf16)v;
  }
  sums[(size_t)blockIdx.x * HD_ + t] = acc;
}

// ---- K2: exclusive scan of chunk sums over c -------------------------------
__global__ __launch_bounds__(512) void k_scan_offsets(const float* __restrict__ sums,
                                                      float* __restrict__ offs) {
  const int b = blockIdx.x, t = threadIdx.x;
  float run = 0.f;
  #pragma unroll 16
  for (int c = 0; c < NCH; ++c) {
    size_t idx = ((size_t)b * NCH + c) * HD_ + t;
    float v = sums[idx];
    offs[idx] = run;
    run += v;
  }
}

// ---- K3: prefix + LayerNorm, emit bf16 ln-half of Abf ----------------------
__global__ __launch_bounds__(512) void k_ln(const float* __restrict__ offs,
                                            const float* __restrict__ gamma,
                                            const float* __restrict__ beta,
                                            __bf16* __restrict__ Abf) {
  __shared__ float2 red[2][8];
  const int t = threadIdx.x, h = t >> 6, d = t & 63;
  const int b = blockIdx.x >> 8, c = blockIdx.x & 255;
  const size_t rT0 = ((size_t)(b * H_ + h)) * S_ + c * LCH;
  float run = offs[(size_t)blockIdx.x * HD_ + t];
  const float g = gamma[t], be = beta[t];
  for (int i = 0; i < LCH; ++i) {
    float xv = (float)Abf[(rT0 + i) * 128 + d];
    float v = run, v2 = run * run;
    #pragma unroll
    for (int o = 32; o; o >>= 1) { v += __shfl_xor(v, o); v2 += __shfl_xor(v2, o); }
    if ((t & 63) == 0) red[i & 1][h] = make_float2(v, v2);
    __syncthreads();
    float s1 = 0.f, s2 = 0.f;
    #pragma unroll
    for (int w = 0; w < 8; ++w) { s1 += red[i & 1][w].x; s2 += red[i & 1][w].y; }
    float m = s1 * (1.f / HD_);
    float var = fmaf(-m, m, s2 * (1.f / HD_));
    float inv = rsqrtf(var + 1e-5f);
    Abf[(rT0 + i) * 128 + 64 + d] = (__bf16)((run - m) * inv * g + be);
    run += xv;
  }
}

// ---- K4: gates MFMA GEMM (coalesced h-major tiles) -> (cA, cB) -------------
__global__ __launch_bounds__(256) void k_gates(const __bf16* __restrict__ Abf,
                                               const __bf16* __restrict__ WthS,
                                               const float* __restrict__ bh,
                                               float* __restrict__ cA,
                                               float* __restrict__ cB) {
  const int t = threadIdx.x;
  const int wave = t >> 6, lane = t & 63;
  const int quad = lane >> 4, l16 = lane & 15;
  const int b = blockIdx.x >> 8, c = blockIdx.x & 255;

  f32x4 acc[2][12];
  #pragma unroll
  for (int i = 0; i < 2; ++i)
    #pragma unroll
    for (int j = 0; j < 12; ++j) acc[i][j] = (f32x4){0.f, 0.f, 0.f, 0.f};

  #pragma unroll
  for (int ks = 0; ks < 4; ++ks) {
    bf16x8 bfrag[12];
    #pragma unroll
    for (int nt = 0; nt < 12; ++nt)
      bfrag[nt] = *(const bf16x8*)(WthS + (size_t)((ks * 12 + nt) * 64 + lane) * 8);
    #pragma unroll
    for (int mi = 0; mi < 2; ++mi) {
      int h = wave * 2 + mi;
      size_t arow = ((size_t)(b * H_ + h)) * S_ + c * LCH + l16;   // contiguous rows
      bf16x8 afrag = *(const bf16x8*)(Abf + arow * 128 + ks * 32 + quad * 8);
      #pragma unroll
      for (int nt = 0; nt < 12; ++nt)
        acc[mi][nt] = __builtin_amdgcn_mfma_f32_16x16x32_bf16(afrag, bfrag[nt], acc[mi][nt], 0, 0, 0);
    }
  }

  #pragma unroll
  for (int mi = 0; mi < 2; ++mi) {
    int h = wave * 2 + mi;
    #pragma unroll
    for (int nt = 0; nt < 4; ++nt) {
      int d = nt * 16 + l16;
      float bi = bh[d], bf = bh[64 + d], bhv = bh[128 + d];
      float A = 1.f, Bv = 0.f;
      #pragma unroll
      for (int r = 0; r < 4; ++r) {
        float f = sigm(acc[mi][nt + 4][r] + bf);
        float g = sigm(acc[mi][nt][r] + bi) * fmaxf(acc[mi][nt + 8][r] + bhv, 0.f);
        A = f * A;
        Bv = fmaf(f, Bv, g);
      }
      float At = 0.f, Bt = 0.f;
      #pragma unroll
      for (int q = 0; q < 4; ++q) {
        float Aq = __shfl(A, q * 16 + l16);
        float Bq = __shfl(Bv, q * 16 + l16);
        if (q == 0) { At = Aq; Bt = Bq; }
        else { At = Aq * At; Bt = fmaf(Aq, Bt, Bq); }
      }
      if (quad == 0) {
        cA[(size_t)blockIdx.x * HD_ + h * 64 + d] = At;
        cB[(size_t)blockIdx.x * HD_ + h * 64 + d] = Bt;
      }
    }
  }
}

// ---- K5: cross-chunk scan -> cin -------------------------------------------
__global__ __launch_bounds__(512) void k_cell_scan(const float* __restrict__ cA,
                                                   const float* __restrict__ cB,
                                                   const float* __restrict__ initcx,
                                                   float* __restrict__ cin) {
  const int b = blockIdx.x, t = threadIdx.x;
  float run = initcx[t];
  #pragma unroll 16
  for (int c = 0; c < NCH; ++c) {
    size_t idx = ((size_t)b * NCH + c) * HD_ + t;
    float a = cA[idx], bb = cB[idx];
    cin[idx] = run;
    run = fmaf(a, run, bb);
  }
}

// ---- K6: gates recompute + in-reg scan + og GEMM + out=og*cell (LDS-staged)
__global__ __launch_bounds__(256) void k_og(const __bf16* __restrict__ Abf,
                                            const __bf16* __restrict__ WthS,
                                            const float* __restrict__ bh,
                                            const __bf16* __restrict__ WtoS,
                                            const float* __restrict__ bo,
                                            const float* __restrict__ cin,
                                            float* __restrict__ out) {
  __shared__ float cl[RC * 68];
  const int t = threadIdx.x;
  const int wave = t >> 6, lane = t & 63;
  const int quad = lane >> 4, l16 = lane & 15;
  const int b = blockIdx.x >> 8, c = blockIdx.x & 255;

  f32x4 acc[2][12];
  #pragma unroll
  for (int i = 0; i < 2; ++i)
    #pragma unroll
    for (int j = 0; j < 12; ++j) acc[i][j] = (f32x4){0.f, 0.f, 0.f, 0.f};

  #pragma unroll
  for (int ks = 0; ks < 4; ++ks) {
    bf16x8 bfrag[12];
    #pragma unroll
    for (int nt = 0; nt < 12; ++nt)
      bfrag[nt] = *(const bf16x8*)(WthS + (size_t)((ks * 12 + nt) * 64 + lane) * 8);
    #pragma unroll
    for (int mi = 0; mi < 2; ++mi) {
      int h = wave * 2 + mi;
      size_t arow = ((size_t)(b * H_ + h)) * S_ + c * LCH + l16;
      bf16x8 afrag = *(const bf16x8*)(Abf + arow * 128 + ks * 32 + quad * 8);
      #pragma unroll
      for (int nt = 0; nt < 12; ++nt)
        acc[mi][nt] = __builtin_amdgcn_mfma_f32_16x16x32_bf16(afrag, bfrag[nt], acc[mi][nt], 0, 0, 0);
    }
  }

  // activations + in-lane scan + cross-quad exclusive prefix seeded by cin.
  // Each wave owns rows of its two h's in cl -> no cross-wave hazard yet.
  #pragma unroll
  for (int mi = 0; mi < 2; ++mi) {
    int h = wave * 2 + mi;
    #pragma unroll
    for (int nt = 0; nt < 4; ++nt) {
      int d = nt * 16 + l16;
      float bi = bh[d], bf = bh[64 + d], bhv = bh[128 + d];
      float fr[4], gr[4];
      float A = 1.f, Bv = 0.f;
      #pragma unroll
      for (int r = 0; r < 4; ++r) {
        fr[r] = sigm(acc[mi][nt + 4][r] + bf);
        gr[r] = sigm(acc[mi][nt][r] + bi) * fmaxf(acc[mi][nt + 8][r] + bhv, 0.f);
        A = fr[r] * A;
        Bv = fmaf(fr[r], Bv, gr[r]);
      }
      float cv = cin[(size_t)blockIdx.x * HD_ + h * 64 + d];
      #pragma unroll
      for (int q = 0; q < 3; ++q) {
        float Aq = __shfl(A, q * 16 + l16);
        float Bq = __shfl(Bv, q * 16 + l16);
        if (q < quad) cv = fmaf(Aq, cv, Bq);
      }
      #pragma unroll
      for (int r = 0; r < 4; ++r) {
        cv = fmaf(fr[r], cv, gr[r]);
        cl[(h * 16 + quad * 4 + r) * 68 + d] = cv;
      }
    }
  }

  // og GEMM: A = [x | cell]; each wave reads only its own h-rows of cl.
  f32x4 acc2[2][4];
  #pragma unroll
  for (int i = 0; i < 2; ++i)
    #pragma unroll
    for (int j = 0; j < 4; ++j) acc2[i][j] = (f32x4){0.f, 0.f, 0.f, 0.f};

  #pragma unroll
  for (int ks = 0; ks < 4; ++ks) {
    bf16x8 bfrag[4];
    #pragma unroll
    for (int nt = 0; nt < 4; ++nt)
      bfrag[nt] = *(const bf16x8*)(WtoS + (size_t)((ks * 4 + nt) * 64 + lane) * 8);
    #pragma unroll
    for (int mi = 0; mi < 2; ++mi) {
      int h = wave * 2 + mi;
      bf16x8 afrag;
      if (ks < 2) {
        size_t arow = ((size_t)(b * H_ + h)) * S_ + c * LCH + l16;
        afrag = *(const bf16x8*)(Abf + arow * 128 + ks * 32 + quad * 8);
      } else {
        const float* src = &cl[(h * 16 + l16) * 68 + (ks - 2) * 32 + quad * 8];
        #pragma unroll
        for (int j = 0; j < 8; ++j) afrag[j] = (__bf16)src[j];
      }
      #pragma unroll
      for (int nt = 0; nt < 4; ++nt)
        acc2[mi][nt] = __builtin_amdgcn_mfma_f32_16x16x32_bf16(afrag, bfrag[nt], acc2[mi][nt], 0, 0, 0);
    }
  }

  // out = sigm(og)*cell, in place in cl (each lane owns its (s,d) slots)
  #pragma unroll
  for (int mi = 0; mi < 2; ++mi) {
    int h = wave * 2 + mi;
    #pragma unroll
    for (int nt = 0; nt < 4; ++nt) {
      int d = nt * 16 + l16;
      float bv = bo[d];
      #pragma unroll
      for (int r = 0; r < 4; ++r) {
        int s = quad * 4 + r;
        float og = sigm(acc2[mi][nt][r] + bv);
        cl[(h * 16 + s) * 68 + d] = og * cl[(h * 16 + s) * 68 + d];
      }
    }
  }
  __syncthreads();

  // coalesced float4 writes: block's out region is 32KB contiguous
  const size_t base4 = (size_t)blockIdx.x * 2048;   // float4 units
  #pragma unroll
  for (int rep = 0; rep < 8; ++rep) {
    int j = rep * 256 + t;
    int s = j >> 7, h2 = (j >> 4) & 7, d4 = j & 15;
    float4 v = *(const float4*)&cl[(h2 * 16 + s) * 68 + d4 * 4];
    ((float4*)out)[base4 + j] = v;
  }
}

extern "C" void kernel_launch(void* const* d_in, const int* in_sizes, int n_in,
                              void* d_out, int out_size, void* d_ws, size_t ws_size,
                              hipStream_t stream) {
  const float* x      = (const float*)d_in[0];
  const float* W_hid  = (const float*)d_in[1];
  const float* b_hid  = (const float*)d_in[2];
  const float* W_og   = (const float*)d_in[3];
  const float* b_og   = (const float*)d_in[4];
  const float* gamma  = (const float*)d_in[5];
  const float* beta   = (const float*)d_in[6];
  const float* initcx = (const float*)d_in[7];
  float* out = (float*)d_out;
  float* ws  = (float*)d_ws;

  const size_t SM = 524288;  // B*NCH*HD floats (2 MB)
  float*  sums = ws;
  float*  offs = sums + SM;
  float*  cA   = offs + SM;
  float*  cB   = cA + SM;
  float*  cin  = cB + SM;
  __bf16* Abf  = (__bf16*)(cin + SM);        // [ (b,h,s) ][128] bf16 = 33.5 MB
  __bf16* WthS = (__bf16*)(Abf + (size_t)131072 * 128);
  __bf16* WtoS = WthS + 24576;

  k_wt          <<<128,  256, 0, stream>>>(W_hid, W_og, WthS, WtoS);
  k_pre         <<<1024, 512, 0, stream>>>(x, sums, Abf);
  k_scan_offsets<<<4,    512, 0, stream>>>(sums, offs);
  k_ln          <<<1024, 512, 0, stream>>>(offs, gamma, beta, Abf);
  k_gates       <<<1024, 256, 0, stream>>>(Abf, WthS, b_hid, cA, cB);
  k_cell_scan   <<<4,    512, 0, stream>>>(cA, cB, initcx, cin);
  k_og          <<<1024, 256, 0, stream>>>(Abf, WthS, b_hid, WtoS, b_og, cin, out);
}